// Round 6
// baseline (850.790 us; speedup 1.0000x reference)
//
#include <hip/hip_runtime.h>
#include <cstdint>
#include <cstddef>

typedef __bf16 bf16x8 __attribute__((ext_vector_type(8)));
typedef float f32x4 __attribute__((ext_vector_type(4)));
typedef float f32x16 __attribute__((ext_vector_type(16)));
typedef unsigned short ushortx8 __attribute__((ext_vector_type(8)));

// float -> bf16, round-half-up
__device__ __forceinline__ unsigned short f2bf(float f) {
  union { float f; unsigned int u; } v; v.f = f;
  return (unsigned short)((v.u + 0x8000u) >> 16);
}

// GELU via 0.5*(1+tanh(t)) == sigmoid(2t); same function as rounds 1-5.
__device__ __forceinline__ float gelu_s(float x) {
  float x2 = x * x;
  float p = __builtin_fmaf(x2, -0.10294324f, -2.30220819f);
  float e = __builtin_amdgcn_exp2f(x * p);
  return x * __builtin_amdgcn_rcpf(1.0f + e);
}

// async global->LDS, 16B/lane. LDS dest is wave-uniform base + lane*16.
#define GLOAD16(gsrc, ldst)                                                  \
  __builtin_amdgcn_global_load_lds(                                          \
      (const __attribute__((address_space(1))) unsigned int*)(gsrc),         \
      (__attribute__((address_space(3))) unsigned int*)(uintptr_t)(          \
          (char*)(ldst)),                                                    \
      16, 0, 0)

// 16x16 swizzled tile (used by k_logits): chunk (row R, col8 C) at
// (R>>5)*4096 + ((R&31)*8 + (C ^ (R&7)))*16
#define SWZ_FRAG(base, R, C8)                                                \
  (*(const bf16x8*)((base) + (((R) >> 5) * 4096) +                           \
                    ((((R)&31) * 8 + ((C8) ^ ((R)&7))) * 16)))

// ---------------------------------------------------------------------------
// Conversion: z -> bf16; W1[g,d,h] -> W1t[g,h,d] bf16; Wc[d,g] -> Wct[g,d]
// ---------------------------------------------------------------------------
__global__ __launch_bounds__(256) void k_convert(
    const float* __restrict__ z, const float* __restrict__ W1,
    const float* __restrict__ Wc, unsigned short* __restrict__ zb,
    unsigned short* __restrict__ w1t, unsigned short* __restrict__ wct) {
  int bid = blockIdx.x;
  int tid = threadIdx.x;
  if (bid < 16384) {
    size_t i = ((size_t)bid * 256 + tid) * 8;
    const float4* p = (const float4*)(z + i);
    float4 a = p[0], b = p[1];
    ushortx8 r;
    r[0] = f2bf(a.x); r[1] = f2bf(a.y); r[2] = f2bf(a.z); r[3] = f2bf(a.w);
    r[4] = f2bf(b.x); r[5] = f2bf(b.y); r[6] = f2bf(b.z); r[7] = f2bf(b.w);
    *(ushortx8*)(zb + i) = r;
  } else if (bid < 16384 + 1024) {
    // W1 transpose via 32x32 LDS tile, both sides coalesced
    __shared__ float tile[32][33];
    int b = bid - 16384;
    int gg = b >> 6;
    int t = b & 63;
    int d0 = (t >> 2) * 32;
    int h0 = (t & 3) * 32;
    int tx = tid & 31, ty = tid >> 5;
#pragma unroll
    for (int r = 0; r < 4; ++r) {
      int d = d0 + r * 8 + ty;
      tile[r * 8 + ty][tx] = W1[(gg << 16) + d * 128 + h0 + tx];
    }
    __syncthreads();
#pragma unroll
    for (int r = 0; r < 4; ++r) {
      int h = h0 + r * 8 + ty;
      w1t[(gg << 16) + h * 512 + d0 + tx] = f2bf(tile[tx][r * 8 + ty]);
    }
  } else {
#pragma unroll
    for (int j = 0; j < 32; ++j) {
      int i = j * 256 + tid;
      wct[(i & 15) * 512 + (i >> 4)] = f2bf(Wc[i]);
    }
  }
}

// ---------------------------------------------------------------------------
// Logits: logits = z @ Wc + bc, softmax. 512 blocks x 128 rows.
// ---------------------------------------------------------------------------
__global__ __launch_bounds__(256) void k_logits(
    const unsigned short* __restrict__ zb,
    const unsigned short* __restrict__ wct, const float* __restrict__ bc,
    float* __restrict__ out) {
  __shared__ alignas(16) char lds[16384];
  const int tid = threadIdx.x;
  const int wq = tid >> 6;
  const int ln = tid & 63;
  const int l15 = ln & 15;
  const int l4 = ln >> 4;
  const int c8s = (((tid & 7) ^ ((tid >> 3) & 7))) * 8;
  const int mbase = blockIdx.x * 128;
  const unsigned short* ag = zb + (size_t)(mbase + (tid >> 3)) * 512 + c8s;
  const unsigned short* wb = wct + l15 * 512 + l4 * 8;
  f32x4 acc2[2] = {};
  for (int kt = 0; kt < 8; ++kt) {
    const int ko = kt * 64;
#pragma unroll
    for (int it = 0; it < 4; ++it)
      GLOAD16(ag + it * 32 * 512 + ko, lds + it * 4096 + tid * 16);
    bf16x8 bfr0 = *(const bf16x8*)(wb + ko);
    bf16x8 bfr1 = *(const bf16x8*)(wb + ko + 32);
    __syncthreads();
#pragma unroll
    for (int rt = 0; rt < 2; ++rt) {
      bf16x8 a0 = SWZ_FRAG(lds, wq * 32 + rt * 16 + l15, l4);
      acc2[rt] =
          __builtin_amdgcn_mfma_f32_16x16x32_bf16(a0, bfr0, acc2[rt], 0, 0, 0);
      bf16x8 a1 = SWZ_FRAG(lds, wq * 32 + rt * 16 + l15, 4 + l4);
      acc2[rt] =
          __builtin_amdgcn_mfma_f32_16x16x32_bf16(a1, bfr1, acc2[rt], 0, 0, 0);
    }
    __syncthreads();
  }
  float bcv = bc[l15];
#pragma unroll
  for (int rt = 0; rt < 2; ++rt) {
#pragma unroll
    for (int i = 0; i < 4; ++i) {
      int row = wq * 32 + rt * 16 + l4 * 4 + i;
      float lg = acc2[rt][i] + bcv;
      float mx = lg;
#pragma unroll
      for (int off = 1; off < 16; off <<= 1)
        mx = fmaxf(mx, __shfl_xor(mx, off, 16));
      float ex = __expf(lg - mx);
      float sm = ex;
#pragma unroll
      for (int off = 1; off < 16; off <<= 1)
        sm += __shfl_xor(sm, off, 16);
      size_t ro = (size_t)(mbase + row) * 16 + l15;
      out[ro] = lg;
      out[1048576 + ro] = ex / sm;
    }
  }
}

// ---------------------------------------------------------------------------
// Expert kernel: persistent over m. grid = 64 m-groups x 16 experts
// (m-major). Block = 1 expert x 1024 rows (16 iters x 64 rows).
// B (64 cols x 256 k-half per wave) lives in 128 VGPRs for the whole kernel.
// Waves: kh = wv>>1 (k-half), ch = wv&1 (col-half). 32x32x16 MFMA.
// A tile (64 rows x 512 k, XOR-swizzled) staged per iter via global_load_lds.
// Cross-k reduce: ct-swap through LDS (each wave donates one 32-col tile,
// keeps the other -> gelu/dot work evenly split across all 4 waves).
// ---------------------------------------------------------------------------
__global__ __launch_bounds__(256, 2) void k_main(
    const unsigned short* __restrict__ zb,   // [65536][512] bf16
    const unsigned short* __restrict__ w1t,  // [16][128][512] bf16
    const float* __restrict__ b1, const float* __restrict__ w2,
    const float* __restrict__ b2, float* __restrict__ out) {
  __shared__ alignas(16) char lds[65536];  // A tile; scratch overlays it
  const int tid = threadIdx.x;
  const int wv = tid >> 6;
  const int ln = tid & 63;
  const int l31 = ln & 31;
  const int l5 = ln >> 5;
  const int kh = wv >> 1;
  const int ch = wv & 1;
  const int e = blockIdx.x & 15;
  const int mg = blockIdx.x >> 4;
  const size_t m0g = (size_t)mg * 1024;

  // ---- B into registers: 2 ct x 16 ks x 16B = 128 VGPRs ----
  bf16x8 bfr[2][16];
  {
    const unsigned short* bp =
        w1t + e * 65536 + (ch * 64 + l31) * 512 + kh * 256 + l5 * 8;
#pragma unroll
    for (int ct = 0; ct < 2; ++ct)
#pragma unroll
      for (int ks = 0; ks < 16; ++ks)
        bfr[ct][ks] = *(const bf16x8*)(bp + ct * 16384 + ks * 16);
  }
  const int col = ch * 64 + kh * 32 + l31;  // the column this wave keeps
  const float b1v = b1[e * 128 + col];
  const float w2v = w2[e * 128 + col];
  const float b2v = b2[e];

  // A staging: chunk c = it2*256+tid -> row R = it2*4 + wv, slot Cs = tid&63,
  // source col8 C = Cs ^ (R&7). Two bases cover even/odd it2.
  const int Ce = (tid & 63) ^ wv;
  const unsigned short* agE = zb + (m0g + wv) * 512 + Ce * 8;
  const unsigned short* agO = zb + (m0g + wv) * 512 + (Ce ^ 4) * 8;

  // A-frag LDS bases: addr = rt*32768 + l31*1024 + kh*512 + (ks>>2)*128
  //                        + (((ks&3)*2 + l5) ^ (l31&7))*16
  int abase[4];
#pragma unroll
  for (int j = 0; j < 4; ++j)
    abase[j] = l31 * 1024 + kh * 512 + (((j * 2 + l5) ^ (l31 & 7)) * 16);

  // scratch (overlaying A buf): W1(ct0, writer kh1)@0, W2(ct1, writer kh0)
  // @16384, ypart @32768. Col slot cs = ch*32+l31, row-chunk swizzled.
  const int cs = ch * 32 + l31;
  const int csx = cs & 7;

  for (int it = 0; it < 16; ++it) {
    f32x16 acc[2][2] = {};
    // ---- stage A(it): 64 rows x 512 k ----
#pragma unroll
    for (int it2 = 0; it2 < 16; ++it2) {
      const unsigned short* src =
          ((it2 & 1) ? agO : agE) + (it * 64 + it2 * 4) * 512;
      GLOAD16(src, lds + it2 * 4096 + tid * 16);
    }
    __syncthreads();
    // ---- compute: 64 MFMA ----
#pragma unroll
    for (int ks = 0; ks < 16; ++ks) {
      const int ao = abase[ks & 3] + (ks >> 2) * 128;
      bf16x8 af0 = *(const bf16x8*)(lds + ao);
      bf16x8 af1 = *(const bf16x8*)(lds + ao + 32768);
      acc[0][0] = __builtin_amdgcn_mfma_f32_32x32x16_bf16(af0, bfr[0][ks],
                                                          acc[0][0], 0, 0, 0);
      acc[0][1] = __builtin_amdgcn_mfma_f32_32x32x16_bf16(af0, bfr[1][ks],
                                                          acc[0][1], 0, 0, 0);
      acc[1][0] = __builtin_amdgcn_mfma_f32_32x32x16_bf16(af1, bfr[0][ks],
                                                          acc[1][0], 0, 0, 0);
      acc[1][1] = __builtin_amdgcn_mfma_f32_32x32x16_bf16(af1, bfr[1][ks],
                                                          acc[1][1], 0, 0, 0);
    }
    __syncthreads();
    // ---- donate the non-kept ct tile to the partner k-half ----
    {
      char* reg = lds + (kh ? 0 : 16384);
      const int donate = kh ^ 1;
#pragma unroll
      for (int rt = 0; rt < 2; ++rt)
#pragma unroll
        for (int q = 0; q < 4; ++q) {
          int chunk = rt * 8 + q * 2 + l5;
          f32x4 v;
#pragma unroll
          for (int i = 0; i < 4; ++i) v[i] = acc[rt][donate][q * 4 + i];
          *(f32x4*)(reg + cs * 256 + ((chunk ^ csx) * 16)) = v;
        }
    }
    __syncthreads();
    // ---- receive partner's partial for kept tile; gelu; dot; butterfly ----
    {
      char* reg = lds + (kh ? 16384 : 0);
      float* yp = (float*)(lds + 32768);
#pragma unroll
      for (int rt = 0; rt < 2; ++rt) {
        float s[16];
#pragma unroll
        for (int q = 0; q < 4; ++q) {
          int chunk = rt * 8 + q * 2 + l5;
          f32x4 v = *(const f32x4*)(reg + cs * 256 + ((chunk ^ csx) * 16));
#pragma unroll
          for (int i = 0; i < 4; ++i) {
            float h = acc[rt][kh][q * 4 + i] + v[i] + b1v;
            s[q * 4 + i] = gelu_s(h) * w2v;
          }
        }
#pragma unroll
        for (int off = 1; off < 32; off <<= 1)
#pragma unroll
          for (int j = 0; j < 16; ++j) s[j] += __shfl_xor(s[j], off, 64);
        if (l31 == 0) {
#pragma unroll
          for (int q = 0; q < 4; ++q) {
            f32x4 v;
#pragma unroll
            for (int i = 0; i < 4; ++i) v[i] = s[q * 4 + i];
            *(f32x4*)(yp + wv * 64 + rt * 32 + q * 8 + l5 * 4) = v;
          }
        }
      }
    }
    __syncthreads();
    // ---- final cross-wave sum + store ----
    if (wv == 0) {
      const float* yp = (const float*)(lds + 32768);
      float y = yp[ln] + yp[64 + ln] + yp[128 + ln] + yp[192 + ln] + b2v;
      out[(size_t)2097152 + (m0g + it * 64 + ln) * 16 + e] = y;
    }
    __syncthreads();
  }
}

// ---------------------------------------------------------------------------
extern "C" void kernel_launch(void* const* d_in, const int* in_sizes, int n_in,
                              void* d_out, int out_size, void* d_ws,
                              size_t ws_size, hipStream_t stream) {
  const float* z = (const float*)d_in[0];
  const float* Wc = (const float*)d_in[1];
  const float* bc = (const float*)d_in[2];
  const float* W1 = (const float*)d_in[3];
  const float* b1 = (const float*)d_in[4];
  const float* W2 = (const float*)d_in[5];
  const float* b2 = (const float*)d_in[6];
  float* out = (float*)d_out;

  unsigned short* zb = (unsigned short*)d_ws;            // 64 MB
  unsigned short* w1t = zb + (size_t)65536 * 512;        // 2 MB
  unsigned short* wct = w1t + (size_t)16 * 128 * 512;    // 16 KB

  k_convert<<<16384 + 1024 + 1, 256, 0, stream>>>(z, W1, Wc, zb, w1t, wct);
  k_logits<<<512, 256, 0, stream>>>(zb, wct, bc, out);
  k_main<<<1024, 256, 0, stream>>>(zb, w1t, b1, W2, b2, out);
}